// Round 4
// baseline (123.165 us; speedup 1.0000x reference)
//
#include <hip/hip_runtime.h>

// DWT db4, 6 levels, zero mode. x:[64, 262144] f32 ->
// concat(cA6, cD6, cD5, cD4, cD3, cD2, cD1) flat.
//
// R4: two-kernel split.
//  K1: levels 1+2 fused (86% of traffic). Tile = 512 cA2 outputs, halo 1%,
//      2 barrier phases, float4 loads + float4 (align-4) detail stores.
//      cA1 lives only in LDS; cA2 -> ws (padded row stride 65544).
//  K2: levels 3-6 fused from ws (L3-resident). Same de-interleaved scheme.
//
// dwt: out[g] = sum_m RFILT[m]*src[2g-6+m], zeros outside [0,N).
// De-interleaved E[k]=src[2k], O[k]=src[2k+1]:
//   out_l = sum_t RLO[2t]*E[l+S+t] + RLO[2t+1]*O[l+S+t]  (S=stage shift)

#define NT 256

#define N0 262144
#define M1 131075
#define M2 65541
#define M3 32774
#define M4 16390
#define M5 8198
#define M6 4102
#define WSTRIDE 65544  // ws row stride (mult of 4); needs 64*65544*4 = 16.0 MiB

#define OFF_A6 ((size_t)0)
#define OFF_D6 ((size_t)262528)
#define OFF_D5 ((size_t)525056)
#define OFF_D4 ((size_t)1049728)
#define OFF_D3 ((size_t)2098688)
#define OFF_D2 ((size_t)4196224)
#define OFF_D1 ((size_t)8390848)

typedef float f4_t __attribute__((ext_vector_type(4)));
typedef f4_t f4u_t __attribute__((aligned(4)));  // clang unaligned-vector idiom

__device__ __constant__ float RLO[8] = {
    0.23037781330885523f, 0.7148465705525415f, 0.6308807679295904f,
    -0.02798376941698385f, -0.18703481171888114f, 0.030841381835986965f,
    0.032883011666982945f, -0.010597401784997278f};
__device__ __constant__ float RHI[8] = {
    -0.010597401784997278f, -0.032883011666982945f, 0.030841381835986965f,
    0.18703481171888114f, -0.02798376941698385f, -0.6308807679295904f,
    0.7148465705525415f, -0.23037781330885523f};

// One fast DWT level over NC chunks of 4 outputs.
// src: de-interleaved E/O float4-aligned LDS arrays. SHIFT=1 right after a
// (base-2)-staged buffer, else 0. cA -> LDS (dE2/dO2) or global f4 (gA).
// Details -> gD, clipped to local range [SLO, SHI), nontemporal dwordx4.
template <int NC, int SLO, int SHI, int SHIFT, bool A_GLOBAL, bool A_NT>
__device__ __forceinline__ void level_fast(const f4_t* __restrict__ sE4,
                                           const f4_t* __restrict__ sO4,
                                           float2* __restrict__ dE2,
                                           float2* __restrict__ dO2,
                                           float* __restrict__ gA,
                                           float* __restrict__ gD) {
  for (int c = threadIdx.x; c < NC; c += NT) {
    f4_t e0 = sE4[c], e1 = sE4[c + 1];
    f4_t o0 = sO4[c], o1 = sO4[c + 1];
    float e[8] = {e0.x, e0.y, e0.z, e0.w, e1.x, e1.y, e1.z, e1.w};
    float o[8] = {o0.x, o0.y, o0.z, o0.w, o1.x, o1.y, o1.z, o1.w};
    float a[4], d[4];
#pragma unroll
    for (int j = 0; j < 4; ++j) {
      float aa = 0.f, dd = 0.f;
#pragma unroll
      for (int t = 0; t < 4; ++t) {
        float ev = e[j + t + SHIFT], ov = o[j + t + SHIFT];
        aa = fmaf(RLO[2 * t], ev, aa);
        aa = fmaf(RLO[2 * t + 1], ov, aa);
        dd = fmaf(RHI[2 * t], ev, dd);
        dd = fmaf(RHI[2 * t + 1], ov, dd);
      }
      a[j] = aa;
      d[j] = dd;
    }
    if (A_GLOBAL) {
      f4_t av = {a[0], a[1], a[2], a[3]};
      if (A_NT)
        __builtin_nontemporal_store(av, (f4u_t*)(gA + 4 * c));
      else
        *(f4u_t*)(gA + 4 * c) = av;
    } else {
      dE2[c] = make_float2(a[0], a[2]);
      dO2[c] = make_float2(a[1], a[3]);
    }
    const int l0 = 4 * c;
    const int lo = l0 < SLO ? SLO : l0;
    const int hi = (l0 + 4) < SHI ? (l0 + 4) : SHI;
    if (lo == l0 && hi == l0 + 4) {
      f4_t dv = {d[0], d[1], d[2], d[3]};
      __builtin_nontemporal_store(dv, (f4u_t*)(gD + l0));
    } else {
      for (int j = lo - l0; j < hi - l0; ++j)
        __builtin_nontemporal_store(d[j], gD + l0 + j);
    }
  }
}

// ============================ K1: levels 1+2 ============================
// tile q (0..128): cA2/cD2 own [512q, 512q+512); cD1 own [1024q, 1024q+1024).
// b1h = 1024q-6 (cA1 window base), b0h = 2048q-18 (x window base).
// LDS: E' 1036 | O' 1036 | E1 520 | O1 520  (12.4 KB)
__global__ __launch_bounds__(NT, 8) void dwt_k1(const float* __restrict__ x,
                                                float* __restrict__ out,
                                                float* __restrict__ ws) {
  const int q = blockIdx.x;
  const int row = blockIdx.y;
  const int tid = threadIdx.x;
  __shared__ float lds[3112];

  const int b2 = q << 9;
  const int b1h = (q << 10) - 6;
  const int b0h = (q << 11) - 18;

  float* gD1 = out + OFF_D1 + (size_t)row * M1 + b1h;
  float* gD2 = out + OFF_D2 + (size_t)row * M2 + b2;
  float* gA2 = ws + (size_t)row * WSTRIDE + b2;

  if (q >= 1 && q <= 127) {
    // stage x[b0h-2 .. b0h+2065] (aligned f4), de-interleave with shift:
    // E'[k] = xloc[2k-2], O'[k] = xloc[2k-1]
    const f4_t* __restrict__ xs4 =
        (const f4_t*)(x + (size_t)row * N0 + (b0h - 2));
    float2* Ep2 = (float2*)(lds + 0);
    float2* Op2 = (float2*)(lds + 1036);
    for (int m = tid; m < 517; m += NT) {
      f4_t v = xs4[m];
      Ep2[m] = make_float2(v.x, v.z);
      Op2[m] = make_float2(v.y, v.w);
    }
    __syncthreads();
    // lvl1: 258 chunks (l<1032, valid<1030), cD1 stores clipped to [6,1030)
    level_fast<258, 6, 1030, 1, false, false>(
        (const f4_t*)(lds + 0), (const f4_t*)(lds + 1036),
        (float2*)(lds + 2072), (float2*)(lds + 2592), nullptr, gD1);
    __syncthreads();
    // lvl2: 128 chunks, cD2 full range, cA2 -> ws (aligned, cached)
    level_fast<128, 0, 512, 0, true, false>(
        (const f4_t*)(lds + 2072), (const f4_t*)(lds + 2592), nullptr, nullptr,
        gA2, gD2);
  } else {
    // edge q = 0 / 128: flat, bounds-checked
    float* xf = lds;         // 2072
    float* a1 = lds + 2072;  // 1032
    const float* __restrict__ xr = x + (size_t)row * N0;
    for (int l = tid; l < 2072; l += NT) {
      int g = b0h + l;
      xf[l] = (g >= 0 && g < N0) ? xr[g] : 0.f;
    }
    __syncthreads();
    const int own0 = q << 10;
    for (int lA = tid; lA < 1032; lA += NT) {
      int g = b1h + lA;
      float aa = 0.f, dd = 0.f;
      if (g >= 0 && g < M1) {
#pragma unroll
        for (int m = 0; m < 8; ++m) {
          float v = xf[2 * lA + m];
          aa = fmaf(RLO[m], v, aa);
          dd = fmaf(RHI[m], v, dd);
        }
      }
      a1[lA] = aa;
      if (g >= own0 && g < own0 + 1024 && g < M1)
        __builtin_nontemporal_store(dd, gD1 + lA);
    }
    __syncthreads();
    for (int l = tid; l < 512; l += NT) {
      int g2 = b2 + l;
      if (g2 < M2) {
        float aa = 0.f, dd = 0.f;
#pragma unroll
        for (int m = 0; m < 8; ++m) {
          float v = a1[2 * l + m];
          aa = fmaf(RLO[m], v, aa);
          dd = fmaf(RHI[m], v, dd);
        }
        __builtin_nontemporal_store(dd, gD2 + l);
        gA2[l] = aa;
      }
    }
  }
}

// ============================ K2: levels 3-6 ============================
// tile p (0..64): 64 cA6 outputs. b2t = 1024p-90 (cA2 window), LEN2t = 1114.
// LDS: E' 560 | O' 560 | E3 280 | O3 280  (6.7 KB); lvl4 reuses E'/O',
// lvl5 reuses E3/O3.
__global__ __launch_bounds__(NT, 8) void dwt_k2(const float* __restrict__ ws,
                                                float* __restrict__ out) {
  const int p = blockIdx.x;
  const int row = blockIdx.y;
  const int tid = threadIdx.x;
  __shared__ float lds[1680];

  const int b6 = p << 6;
  const int b5 = (p << 7) - 6;
  const int b4 = (p << 8) - 18;
  const int b3 = (p << 9) - 42;
  const int b2t = (p << 10) - 90;

  float* gD3 = out + OFF_D3 + (size_t)row * M3 + b3;
  float* gD4 = out + OFF_D4 + (size_t)row * M4 + b4;
  float* gD5 = out + OFF_D5 + (size_t)row * M5 + b5;
  float* gD6 = out + OFF_D6 + (size_t)row * M6 + b6;
  float* gA6 = out + OFF_A6 + (size_t)row * M6 + b6;
  const float* __restrict__ wr = ws + (size_t)row * WSTRIDE;

  if (p >= 1 && p <= 63) {
    const f4_t* __restrict__ s4 = (const f4_t*)(wr + (b2t - 2));
    float2* Ep2 = (float2*)(lds + 0);
    float2* Op2 = (float2*)(lds + 560);
    for (int m = tid; m < 279; m += NT) {
      f4_t v = s4[m];
      Ep2[m] = make_float2(v.x, v.z);
      Op2[m] = make_float2(v.y, v.w);
    }
    __syncthreads();
    level_fast<139, 0, 554, 1, false, false>(
        (const f4_t*)(lds + 0), (const f4_t*)(lds + 560),
        (float2*)(lds + 1120), (float2*)(lds + 1400), nullptr, gD3);
    __syncthreads();
    level_fast<69, 0, 274, 0, false, false>(
        (const f4_t*)(lds + 1120), (const f4_t*)(lds + 1400),
        (float2*)(lds + 0), (float2*)(lds + 560), nullptr, gD4);
    __syncthreads();
    level_fast<34, 0, 134, 0, false, false>(
        (const f4_t*)(lds + 0), (const f4_t*)(lds + 560),
        (float2*)(lds + 1120), (float2*)(lds + 1400), nullptr, gD5);
    __syncthreads();
    level_fast<16, 0, 64, 0, true, true>(
        (const f4_t*)(lds + 1120), (const f4_t*)(lds + 1400), nullptr, nullptr,
        gA6, gD6);
  } else {
    // edge p = 0 / 64: flat, bounds-checked
    float* xf = lds;          // 1120 (window idx <= 1113)
    float* bb = lds + 1120;   // 560: lvl3 out, later lvl5 out
    for (int l = tid; l < 1116; l += NT) {
      int g = b2t + l;
      xf[l] = (g >= 0 && g < M2) ? wr[g] : 0.f;
    }
    __syncthreads();
    for (int l = tid; l < 554; l += NT) {  // lvl3
      int g = b3 + l;
      float aa = 0.f, dd = 0.f;
      if (g >= 0 && g < M3) {
#pragma unroll
        for (int m = 0; m < 8; ++m) {
          float v = xf[2 * l + m];
          aa = fmaf(RLO[m], v, aa);
          dd = fmaf(RHI[m], v, dd);
        }
      }
      bb[l] = aa;
      if (l >= 42 && g < M3) __builtin_nontemporal_store(dd, gD3 + l);
    }
    __syncthreads();
    for (int l = tid; l < 274; l += NT) {  // lvl4 -> lds[0..274)
      int g = b4 + l;
      float aa = 0.f, dd = 0.f;
      if (g >= 0 && g < M4) {
#pragma unroll
        for (int m = 0; m < 8; ++m) {
          float v = bb[2 * l + m];
          aa = fmaf(RLO[m], v, aa);
          dd = fmaf(RHI[m], v, dd);
        }
      }
      lds[l] = aa;
      if (l >= 18 && g < M4) __builtin_nontemporal_store(dd, gD4 + l);
    }
    __syncthreads();
    for (int l = tid; l < 134; l += NT) {  // lvl5 -> bb[0..134)
      int g = b5 + l;
      float aa = 0.f, dd = 0.f;
      if (g >= 0 && g < M5) {
#pragma unroll
        for (int m = 0; m < 8; ++m) {
          float v = lds[2 * l + m];
          aa = fmaf(RLO[m], v, aa);
          dd = fmaf(RHI[m], v, dd);
        }
      }
      bb[l] = aa;
      if (l >= 6 && g < M5) __builtin_nontemporal_store(dd, gD5 + l);
    }
    __syncthreads();
    for (int l = tid; l < 64; l += NT) {  // lvl6
      int g = b6 + l;
      if (g < M6) {
        float aa = 0.f, dd = 0.f;
#pragma unroll
        for (int m = 0; m < 8; ++m) {
          float v = bb[2 * l + m];
          aa = fmaf(RLO[m], v, aa);
          dd = fmaf(RHI[m], v, dd);
        }
        __builtin_nontemporal_store(aa, gA6 + l);
        __builtin_nontemporal_store(dd, gD6 + l);
      }
    }
  }
}

extern "C" void kernel_launch(void* const* d_in, const int* in_sizes, int n_in,
                              void* d_out, int out_size, void* d_ws,
                              size_t ws_size, hipStream_t stream) {
  const float* x = (const float*)d_in[0];
  float* out = (float*)d_out;
  float* ws = (float*)d_ws;  // needs 16.0 MiB; harness provides ~268 MB
  dwt_k1<<<dim3(129, 64), NT, 0, stream>>>(x, out, ws);
  dwt_k2<<<dim3(65, 64), NT, 0, stream>>>(ws, out);
}